// Round 16
// baseline (94.604 us; speedup 1.0000x reference)
//
#include <hip/hip_runtime.h>
#include <hip/hip_bf16.h>
#include <stdint.h>

#define B_ 4
#define C_ 256
#define N_ 4096
#define D_ 32
#define KT 256   // keys per outer iteration
#define NIT (N_ / KT)

typedef __bf16 bf16_t;
typedef __bf16 bf16x4_t __attribute__((ext_vector_type(4)));
typedef __bf16 bf16x8_t __attribute__((ext_vector_type(8)));
typedef float  f32x4    __attribute__((ext_vector_type(4)));

// ---------------------------------------------------------------------------
// Projection GEMM, fully fused: reads W (wq|wk|wv) f32 + x f32 directly.
// Each af fragment group (w,rt) covers 16 rows that lie entirely inside one
// of wq/wk/wv (boundaries 32/64 are multiples of 16) -> uniform base select
// + inline cvt. x staged per k-tile in LDS [64][65], cvt at fragment build.
// Q rows pre-scaled by log2(e) (exp2-domain softmax downstream).
// ---------------------------------------------------------------------------
__global__ __launch_bounds__(256) void proj_kernel(
    const float* __restrict__ x,
    const float* __restrict__ wq, const float* __restrict__ wk,
    const float* __restrict__ wv,
    const float* __restrict__ bq, const float* __restrict__ bk,
    const float* __restrict__ bv,
    bf16_t* __restrict__ Qh, bf16_t* __restrict__ Kh, bf16_t* __restrict__ Vh)
{
  __shared__ float xs[64][65];
  const int bi = blockIdx.x;
  const int b  = bi & 3;
  const int n0 = (bi >> 2) * 64;
  const int t = threadIdx.x, w = t >> 6, lane = t & 63;
  const int l4 = lane >> 4, lm = lane & 15;

  const f32x4 z4 = {0.f, 0.f, 0.f, 0.f};
  f32x4 acc[5][4];
#pragma unroll
  for (int rt = 0; rt < 5; ++rt)
#pragma unroll
    for (int ct = 0; ct < 4; ++ct) acc[rt][ct] = z4;

  // per-(w,rt) uniform W source (gr0 multiple of 16; boundaries at 32/64)
  const float* wsrc[5];
#pragma unroll
  for (int rt = 0; rt < 5; ++rt) {
    const int gr0 = w * 80 + rt * 16;
    wsrc[rt] = (gr0 < 32) ? (wq + gr0 * C_)
             : (gr0 < 64) ? (wk + (gr0 - 32) * C_)
                          : (wv + (gr0 - 64) * C_);
  }

  const int lr = t >> 2;
  const int lc = (t & 3) * 16;

#pragma unroll 1
  for (int k0 = 0; k0 < C_; k0 += 64) {
    __syncthreads();
#pragma unroll
    for (int i = 0; i < 4; ++i) {
      const f32x4 v = *(const f32x4*)(x + ((size_t)(b * C_ + k0 + lr)) * N_ + n0 + lc + i * 4);
      xs[lr][lc + i * 4 + 0] = v[0];
      xs[lr][lc + i * 4 + 1] = v[1];
      xs[lr][lc + i * 4 + 2] = v[2];
      xs[lr][lc + i * 4 + 3] = v[3];
    }
    __syncthreads();

    bf16x8_t af[5][2], bfr[4][2];
#pragma unroll
    for (int rt = 0; rt < 5; ++rt)
#pragma unroll
      for (int kc = 0; kc < 2; ++kc) {
        const float* p = wsrc[rt] + lm * C_ + k0 + kc * 32 + l4 * 8;
        const f32x4 a0 = *(const f32x4*)p;
        const f32x4 a1 = *(const f32x4*)(p + 4);
        bf16_t tmp[8];
#pragma unroll
        for (int j = 0; j < 4; ++j) { tmp[j] = (bf16_t)a0[j]; tmp[4 + j] = (bf16_t)a1[j]; }
        af[rt][kc] = *(bf16x8_t*)tmp;
      }
#pragma unroll
    for (int ct = 0; ct < 4; ++ct)
#pragma unroll
      for (int kc = 0; kc < 2; ++kc) {
        bf16_t tmp[8];
#pragma unroll
        for (int j = 0; j < 8; ++j)
          tmp[j] = (bf16_t)xs[kc * 32 + l4 * 8 + j][ct * 16 + lm];
        bfr[ct][kc] = *(bf16x8_t*)tmp;
      }
#pragma unroll
    for (int rt = 0; rt < 5; ++rt)
#pragma unroll
      for (int ct = 0; ct < 4; ++ct)
#pragma unroll
        for (int kc = 0; kc < 2; ++kc)
          acc[rt][ct] = __builtin_amdgcn_mfma_f32_16x16x32_bf16(af[rt][kc], bfr[ct][kc], acc[rt][ct], 0, 0, 0);
  }

#pragma unroll
  for (int rt = 0; rt < 5; ++rt)
#pragma unroll
    for (int r = 0; r < 4; ++r) {
      const int gr = w * 80 + rt * 16 + 4 * l4 + r;
      const float bias = (gr < 32) ? bq[gr] : (gr < 64) ? bk[gr - 32] : bv[gr - 64];
#pragma unroll
      for (int ct = 0; ct < 4; ++ct) {
        const int n = n0 + ct * 16 + lm;
        float v = acc[rt][ct][r] + bias;
        if (gr < 32) {
          v *= 1.44269504088896f;
          Qh[((size_t)(b * N_ + n)) * D_ + gr] = (bf16_t)v;
        } else if (gr < 64) {
          Kh[((size_t)(b * N_ + n)) * D_ + (gr - 32)] = (bf16_t)v;
        } else {
          Vh[((size_t)(b * C_ + (gr - 64))) * N_ + n] = (bf16_t)v;
        }
      }
    }
}

// ---------------------------------------------------------------------------
// Flash attention (R15 structure: cross-iter overlap, fixed-reference exp2,
// XOR-swizzled double-buffered P, ONE lgkm barrier/iter) + EPILOGUE X-PREFETCH:
// the 32 x-values/thread are loaded into registers during iter NIT-2 so the
// final out = gamma*acc/l + x burst exposes only the store stream.
// ---------------------------------------------------------------------------
__global__ __launch_bounds__(512, 2) void attn_kernel(
    const bf16_t* __restrict__ Qh, const bf16_t* __restrict__ Kh,
    const bf16_t* __restrict__ Vh, const float* __restrict__ x,
    const float* __restrict__ gamma, float* __restrict__ out)
{
  __shared__ __align__(16) bf16_t Pl[2][64][KT];  // 64 KB double-buffered P
  __shared__ __align__(16) float  Lx[64][12];     // epilogue l exchange

  const int bi = blockIdx.x;
  const int xcd = bi & 7, slot = bi >> 3;
  const int b  = xcd >> 1;                 // 2 XCDs per batch -> K,V,Q L2-resident
  const int q0 = ((xcd & 1) * 32 + slot) * 64;

  const int t = threadIdx.x, w = t >> 6, lane = t & 63;
  const int l4 = lane >> 4, lm = lane & 15;
  const int swz = (lm & 7) << 3;

  const f32x4 z4 = {0.f, 0.f, 0.f, 0.f};

  bf16x8_t qf[4];
#pragma unroll
  for (int rt = 0; rt < 4; ++rt)
    qf[rt] = *(const bf16x8_t*)(Qh + ((size_t)(b * N_ + q0 + rt * 16 + lm)) * D_ + l4 * 8);

  const bf16_t* kbase = Kh + ((size_t)(b * N_ + w * 32 + lm)) * D_ + l4 * 8;
  const bf16_t* vbase = Vh + ((size_t)(b * C_ + w * 32 + lm)) * N_ + l4 * 8;

  f32x4 acc[2][4];
#pragma unroll
  for (int ct = 0; ct < 2; ++ct)
#pragma unroll
    for (int rt = 0; rt < 4; ++rt) acc[ct][rt] = z4;
  float l_run[4] = {0.f, 0.f, 0.f, 0.f};
  float xr[4][2][4];   // epilogue x prefetch (32 f32)

  // ---- prologue ----
  bf16x8_t kf[2], kn[2];
#pragma unroll
  for (int mt = 0; mt < 2; ++mt)
    kf[mt] = *(const bf16x8_t*)(kbase + (size_t)(mt * 16) * D_);
#pragma unroll
  for (int mt = 0; mt < 2; ++mt)
    kn[mt] = *(const bf16x8_t*)(kbase + (size_t)(KT + mt * 16) * D_);
  bf16x8_t vf0[2][2], vf1[2][2];
#pragma unroll
  for (int ct = 0; ct < 2; ++ct)
#pragma unroll
    for (int kc = 0; kc < 2; ++kc) {
      vf0[ct][kc] = *(const bf16x8_t*)(vbase + (size_t)(ct * 16) * N_ + kc * 32);
      vf1[ct][kc] = *(const bf16x8_t*)(vbase + (size_t)(ct * 16) * N_ + 64 + kc * 32);
    }

  f32x4 S[4][2];
#pragma unroll
  for (int rt = 0; rt < 4; ++rt)
#pragma unroll
    for (int mt = 0; mt < 2; ++mt)
      S[rt][mt] = __builtin_amdgcn_mfma_f32_16x16x32_bf16(kf[mt], qf[rt], z4, 0, 0, 0);
#pragma unroll
  for (int rt = 0; rt < 4; ++rt) {
    const int prow = rt * 16 + lm;
#pragma unroll
    for (int mt = 0; mt < 2; ++mt) {
      const float p0 = __builtin_amdgcn_exp2f(S[rt][mt][0]);
      const float p1 = __builtin_amdgcn_exp2f(S[rt][mt][1]);
      const float p2 = __builtin_amdgcn_exp2f(S[rt][mt][2]);
      const float p3 = __builtin_amdgcn_exp2f(S[rt][mt][3]);
      l_run[rt] += (p0 + p1) + (p2 + p3);
      bf16x4_t w4 = {(bf16_t)p0, (bf16_t)p1, (bf16_t)p2, (bf16_t)p3};
      *(bf16x4_t*)&Pl[0][prow][(w * 32 + mt * 16 + 4 * l4) ^ swz] = w4;
    }
  }
  asm volatile("s_waitcnt lgkmcnt(0)" ::: "memory");
  __builtin_amdgcn_s_barrier();

  // ---- main loop: NIT-1 full iters (PV(it) ∥ S/exp2/P-write(it+1)) ----
#pragma unroll 1
  for (int it = 0; it < NIT - 1; ++it) {
    const int buf = it & 1;
    bf16x8_t pa[4][2];

    // ===== s4 = 0 : pa + S(it+1) MFMAs + PV + vf0 reload =====
#pragma unroll
    for (int rt = 0; rt < 4; ++rt)
#pragma unroll
      for (int kc = 0; kc < 2; ++kc)
        pa[rt][kc] = *(const bf16x8_t*)&Pl[buf][rt * 16 + lm][(0 * 64 + kc * 32 + l4 * 8) ^ swz];
#pragma unroll
    for (int rt = 0; rt < 4; ++rt)
#pragma unroll
      for (int mt = 0; mt < 2; ++mt)
        S[rt][mt] = __builtin_amdgcn_mfma_f32_16x16x32_bf16(kn[mt], qf[rt], z4, 0, 0, 0);
#pragma unroll
    for (int ct = 0; ct < 2; ++ct)
#pragma unroll
      for (int kc = 0; kc < 2; ++kc)
#pragma unroll
        for (int rt = 0; rt < 4; ++rt)
          acc[ct][rt] = __builtin_amdgcn_mfma_f32_16x16x32_bf16(vf0[ct][kc], pa[rt][kc], acc[ct][rt], 0, 0, 0);
    {
      const int knx = (it * KT + 2 * 64) & (N_ - 1);
#pragma unroll
      for (int ct = 0; ct < 2; ++ct)
#pragma unroll
        for (int kc = 0; kc < 2; ++kc)
          vf0[ct][kc] = *(const bf16x8_t*)(vbase + (size_t)(ct * 16) * N_ + knx + kc * 32);
    }

    // ===== s4 = 1 : pa + exp2(rt 0..1) + P-write + PV + vf1 reload =====
#pragma unroll
    for (int rt = 0; rt < 4; ++rt)
#pragma unroll
      for (int kc = 0; kc < 2; ++kc)
        pa[rt][kc] = *(const bf16x8_t*)&Pl[buf][rt * 16 + lm][(1 * 64 + kc * 32 + l4 * 8) ^ swz];
#pragma unroll
    for (int rt = 0; rt < 2; ++rt) {
      const int prow = rt * 16 + lm;
#pragma unroll
      for (int mt = 0; mt < 2; ++mt) {
        const float p0 = __builtin_amdgcn_exp2f(S[rt][mt][0]);
        const float p1 = __builtin_amdgcn_exp2f(S[rt][mt][1]);
        const float p2 = __builtin_amdgcn_exp2f(S[rt][mt][2]);
        const float p3 = __builtin_amdgcn_exp2f(S[rt][mt][3]);
        l_run[rt] += (p0 + p1) + (p2 + p3);
        bf16x4_t w4 = {(bf16_t)p0, (bf16_t)p1, (bf16_t)p2, (bf16_t)p3};
        *(bf16x4_t*)&Pl[buf ^ 1][prow][(w * 32 + mt * 16 + 4 * l4) ^ swz] = w4;
      }
    }
#pragma unroll
    for (int ct = 0; ct < 2; ++ct)
#pragma unroll
      for (int kc = 0; kc < 2; ++kc)
#pragma unroll
        for (int rt = 0; rt < 4; ++rt)
          acc[ct][rt] = __builtin_amdgcn_mfma_f32_16x16x32_bf16(vf1[ct][kc], pa[rt][kc], acc[ct][rt], 0, 0, 0);
    {
      const int knx = (it * KT + 3 * 64) & (N_ - 1);
#pragma unroll
      for (int ct = 0; ct < 2; ++ct)
#pragma unroll
        for (int kc = 0; kc < 2; ++kc)
          vf1[ct][kc] = *(const bf16x8_t*)(vbase + (size_t)(ct * 16) * N_ + knx + kc * 32);
    }

    // ===== s4 = 2 : pa + exp2(rt 2..3) + P-write + PV + vf0 reload =====
#pragma unroll
    for (int rt = 0; rt < 4; ++rt)
#pragma unroll
      for (int kc = 0; kc < 2; ++kc)
        pa[rt][kc] = *(const bf16x8_t*)&Pl[buf][rt * 16 + lm][(2 * 64 + kc * 32 + l4 * 8) ^ swz];
#pragma unroll
    for (int rt = 2; rt < 4; ++rt) {
      const int prow = rt * 16 + lm;
#pragma unroll
      for (int mt = 0; mt < 2; ++mt) {
        const float p0 = __builtin_amdgcn_exp2f(S[rt][mt][0]);
        const float p1 = __builtin_amdgcn_exp2f(S[rt][mt][1]);
        const float p2 = __builtin_amdgcn_exp2f(S[rt][mt][2]);
        const float p3 = __builtin_amdgcn_exp2f(S[rt][mt][3]);
        l_run[rt] += (p0 + p1) + (p2 + p3);
        bf16x4_t w4 = {(bf16_t)p0, (bf16_t)p1, (bf16_t)p2, (bf16_t)p3};
        *(bf16x4_t*)&Pl[buf ^ 1][prow][(w * 32 + mt * 16 + 4 * l4) ^ swz] = w4;
      }
    }
#pragma unroll
    for (int ct = 0; ct < 2; ++ct)
#pragma unroll
      for (int kc = 0; kc < 2; ++kc)
#pragma unroll
        for (int rt = 0; rt < 4; ++rt)
          acc[ct][rt] = __builtin_amdgcn_mfma_f32_16x16x32_bf16(vf0[ct][kc], pa[rt][kc], acc[ct][rt], 0, 0, 0);
    {
      const int knx = (it * KT + 4 * 64) & (N_ - 1);
#pragma unroll
      for (int ct = 0; ct < 2; ++ct)
#pragma unroll
        for (int kc = 0; kc < 2; ++kc)
          vf0[ct][kc] = *(const bf16x8_t*)(vbase + (size_t)(ct * 16) * N_ + knx + kc * 32);
    }

    // ===== s4 = 3 : pa + K(it+2) prefetch + PV + vf1 reload =====
#pragma unroll
    for (int rt = 0; rt < 4; ++rt)
#pragma unroll
      for (int kc = 0; kc < 2; ++kc)
        pa[rt][kc] = *(const bf16x8_t*)&Pl[buf][rt * 16 + lm][(3 * 64 + kc * 32 + l4 * 8) ^ swz];
    {
      const int k0n = ((it + 2) * KT) & (N_ - 1);
#pragma unroll
      for (int mt = 0; mt < 2; ++mt)
        kn[mt] = *(const bf16x8_t*)(kbase + (size_t)(k0n + mt * 16) * D_);
    }
#pragma unroll
    for (int ct = 0; ct < 2; ++ct)
#pragma unroll
      for (int kc = 0; kc < 2; ++kc)
#pragma unroll
        for (int rt = 0; rt < 4; ++rt)
          acc[ct][rt] = __builtin_amdgcn_mfma_f32_16x16x32_bf16(vf1[ct][kc], pa[rt][kc], acc[ct][rt], 0, 0, 0);
    {
      const int knx = (it * KT + 5 * 64) & (N_ - 1);
#pragma unroll
      for (int ct = 0; ct < 2; ++ct)
#pragma unroll
        for (int kc = 0; kc < 2; ++kc)
          vf1[ct][kc] = *(const bf16x8_t*)(vbase + (size_t)(ct * 16) * N_ + knx + kc * 32);
    }

    // ===== epilogue x prefetch: issue during iter NIT-2 =====
    if (it == NIT - 3) {
#pragma unroll
      for (int rt = 0; rt < 4; ++rt) {
        const int n = q0 + rt * 16 + lm;
#pragma unroll
        for (int ct = 0; ct < 2; ++ct) {
          const int c = w * 32 + ct * 16 + 4 * l4;
          const float* xp = x + ((size_t)(b * C_ + c)) * N_ + n;
#pragma unroll
          for (int r = 0; r < 4; ++r) xr[rt][ct][r] = xp[(size_t)r * N_];
        }
      }
    }

    asm volatile("s_waitcnt lgkmcnt(0)" ::: "memory");   // P(it+1) visible; buf reads drained
    __builtin_amdgcn_s_barrier();
  }

  // ---- tail: PV(last) only ----
  {
    const int buf = (NIT - 1) & 1;
#pragma unroll
    for (int s4 = 0; s4 < 4; ++s4) {
      bf16x8_t pa[4][2];
#pragma unroll
      for (int rt = 0; rt < 4; ++rt)
#pragma unroll
        for (int kc = 0; kc < 2; ++kc)
          pa[rt][kc] = *(const bf16x8_t*)&Pl[buf][rt * 16 + lm][(s4 * 64 + kc * 32 + l4 * 8) ^ swz];
      if ((s4 & 1) == 0) {
#pragma unroll
        for (int ct = 0; ct < 2; ++ct)
#pragma unroll
          for (int kc = 0; kc < 2; ++kc)
#pragma unroll
            for (int rt = 0; rt < 4; ++rt)
              acc[ct][rt] = __builtin_amdgcn_mfma_f32_16x16x32_bf16(vf0[ct][kc], pa[rt][kc], acc[ct][rt], 0, 0, 0);
      } else {
#pragma unroll
        for (int ct = 0; ct < 2; ++ct)
#pragma unroll
          for (int kc = 0; kc < 2; ++kc)
#pragma unroll
            for (int rt = 0; rt < 4; ++rt)
              acc[ct][rt] = __builtin_amdgcn_mfma_f32_16x16x32_bf16(vf1[ct][kc], pa[rt][kc], acc[ct][rt], 0, 0, 0);
      }
      if (s4 < 2) {
        const int knx = ((NIT - 1) * KT + (s4 + 2) * 64) & (N_ - 1);
        if ((s4 & 1) == 0) {
#pragma unroll
          for (int ct = 0; ct < 2; ++ct)
#pragma unroll
            for (int kc = 0; kc < 2; ++kc)
              vf0[ct][kc] = *(const bf16x8_t*)(vbase + (size_t)(ct * 16) * N_ + knx + kc * 32);
        } else {
#pragma unroll
          for (int ct = 0; ct < 2; ++ct)
#pragma unroll
            for (int kc = 0; kc < 2; ++kc)
              vf1[ct][kc] = *(const bf16x8_t*)(vbase + (size_t)(ct * 16) * N_ + knx + kc * 32);
        }
      }
    }
  }

  // ---- epilogue: reduce l, then store (x already in registers) ----
#pragma unroll
  for (int rt = 0; rt < 4; ++rt) {
    l_run[rt] += __shfl_xor(l_run[rt], 16);
    l_run[rt] += __shfl_xor(l_run[rt], 32);
  }
  if (l4 == 0) {
#pragma unroll
    for (int rt = 0; rt < 4; ++rt) Lx[rt * 16 + lm][w] = l_run[rt];
  }
  asm volatile("s_waitcnt lgkmcnt(0)" ::: "memory");
  __builtin_amdgcn_s_barrier();

  const float g = gamma[0];
#pragma unroll
  for (int rt = 0; rt < 4; ++rt) {
    const f32x4 s0 = *(const f32x4*)&Lx[rt * 16 + lm][0];
    const f32x4 s1 = *(const f32x4*)&Lx[rt * 16 + lm][4];
    const float lt = ((s0[0] + s0[1]) + (s0[2] + s0[3])) + ((s1[0] + s1[1]) + (s1[2] + s1[3]));
    const float inv = 1.f / lt;
    const int n = q0 + rt * 16 + lm;
#pragma unroll
    for (int ct = 0; ct < 2; ++ct) {
#pragma unroll
      for (int r = 0; r < 4; ++r) {
        const int c = w * 32 + ct * 16 + 4 * l4 + r;
        const size_t idx = ((size_t)(b * C_ + c)) * N_ + n;
        out[idx] = g * (acc[ct][rt][r] * inv) + xr[rt][ct][r];
      }
    }
  }
}

extern "C" void kernel_launch(void* const* d_in, const int* in_sizes, int n_in,
                              void* d_out, int out_size, void* d_ws, size_t ws_size,
                              hipStream_t stream) {
  const float* x     = (const float*)d_in[0];
  const float* wq    = (const float*)d_in[1];
  const float* bq    = (const float*)d_in[2];
  const float* wk    = (const float*)d_in[3];
  const float* bk    = (const float*)d_in[4];
  const float* wv    = (const float*)d_in[5];
  const float* bv    = (const float*)d_in[6];
  const float* gamma = (const float*)d_in[7];
  float* out = (float*)d_out;

  bf16_t* Qh = (bf16_t*)d_ws;
  bf16_t* Kh = Qh + (size_t)B_ * N_ * D_;
  bf16_t* Vh = Kh + (size_t)B_ * N_ * D_;

  proj_kernel<<<256, 256, 0, stream>>>(x, wq, wk, wv, bq, bk, bv, Qh, Kh, Vh);
  attn_kernel<<<256, 512, 0, stream>>>(Qh, Kh, Vh, x, gamma, out);
}